// Round 5
// baseline (175.877 us; speedup 1.0000x reference)
//
#include <hip/hip_runtime.h>

typedef __bf16 bf16;
typedef __attribute__((ext_vector_type(8))) __bf16 bf16x8;
typedef __attribute__((ext_vector_type(8))) ushort ushort8v;
typedef __attribute__((ext_vector_type(4))) ushort ushort4v;
typedef __attribute__((ext_vector_type(2))) uint uint2v;
typedef __attribute__((ext_vector_type(4))) float f32x4;

constexpr int S_LEN = 2048;
constexpr int DH    = 64;
constexpr int QBLK  = 64;
constexpr int KVBLK = 64;
constexpr int NWAVE = 4;
constexpr int NT    = S_LEN / KVBLK;            // 32 kv tiles
constexpr float QSCALE = 0.125f * 1.44269504088896f;  // 1/sqrt(64) * log2(e)
constexpr float NEG    = -1.44269504e9f;        // -1e9 in log2 domain
constexpr float THR    = 8.0f;                  // defer-max threshold (T13)
constexpr size_t TILE_BYTES = (size_t)KVBLK * DH * 2;       // 8 KiB
constexpr size_t KV_BYTES   = (size_t)64 * NT * TILE_BYTES; // 16 MiB per tensor

__device__ __forceinline__ ushort bfb(float f) {
  bf16 b = (bf16)f;
  return __builtin_bit_cast(ushort, b);
}
__device__ __forceinline__ int SWZ(int row) {
  return ((row & 7) ^ ((row >> 3) & 7)) << 4;
}
__device__ __forceinline__ uint cvtpk(float lo, float hi) {
  uint r;
  asm("v_cvt_pk_bf16_f32 %0, %1, %2" : "=v"(r) : "v"(lo), "v"(hi));
  return r;
}
__device__ __forceinline__ void gload16(const char* g, void* l) {
  __builtin_amdgcn_global_load_lds(
      (__attribute__((address_space(1))) void*)(g),
      (__attribute__((address_space(3))) void*)(l), 16, 0, 0);
}

// ---- prepass: per q-row-block, 32-bit mask of all-ones 64x64 tiles ----
__global__ __launch_bounds__(256)
void mask_flags(const int* __restrict__ M, uint* __restrict__ F) {
  const int qt = blockIdx.x;
  const int tid = threadIdx.x;
  const int r  = tid >> 2;
  const int c0 = (tid & 3) * 16;
  __shared__ int s[4];
  uint bits = 0;
  for (int kt = 0; kt < NT; ++kt) {
    const int* row = M + (size_t)(qt * 64 + r) * S_LEN + kt * 64 + c0;
    int ok = 1;
#pragma unroll
    for (int i = 0; i < 4; ++i) {
      int4 v = *(const int4*)(row + i * 4);
      ok &= (v.x != 0) & (v.y != 0) & (v.z != 0) & (v.w != 0);
    }
    ok = __all(ok) ? 1 : 0;
    if ((tid & 63) == 0) s[tid >> 6] = ok;
    __syncthreads();
    if (s[0] & s[1] & s[2] & s[3]) bits |= 1u << kt;
    __syncthreads();
  }
  if (tid == 0) F[qt] = bits;
}

// ---- prepass: K -> bf16 swizzled tile blobs; V -> V^T bf16 swizzled blobs ----
__global__ __launch_bounds__(256)
void cvt_kv(const float* __restrict__ K, const float* __restrict__ V,
            char* __restrict__ kws, char* __restrict__ vws) {
  const int t = blockIdx.x, bh = blockIdx.y, tid = threadIdx.x;
  const float* Kb = K + ((size_t)bh * S_LEN + t * KVBLK) * DH;
  const float* Vb = V + ((size_t)bh * S_LEN + t * KVBLK) * DH;
  char* kd = kws + ((size_t)bh * NT + t) * TILE_BYTES;
  char* vd = vws + ((size_t)bh * NT + t) * TILE_BYTES;

  const int kr0 = tid >> 3, kc8 = tid & 7;
#pragma unroll
  for (int h = 0; h < 2; ++h) {
    const int row = kr0 + 32 * h;
    const float* kp = Kb + (size_t)row * DH + kc8 * 8;
    float4 a = *(const float4*)kp;
    float4 b = *(const float4*)(kp + 4);
    ushort8v pk;
    pk[0]=bfb(a.x); pk[1]=bfb(a.y); pk[2]=bfb(a.z); pk[3]=bfb(a.w);
    pk[4]=bfb(b.x); pk[5]=bfb(b.y); pk[6]=bfb(b.z); pk[7]=bfb(b.w);
    *(ushort8v*)(kd + row * 128 + ((kc8 * 16) ^ SWZ(row))) = pk;
  }
  const int vr = (tid >> 4) * 4, vc = (tid & 15) * 4;
  float rr[4][4];
#pragma unroll
  for (int i = 0; i < 4; ++i)
    *(float4*)rr[i] = *(const float4*)(Vb + (size_t)(vr + i) * DH + vc);
#pragma unroll
  for (int c = 0; c < 4; ++c) {
    const int d = vc + c;
    ushort4v p4;
    p4[0]=bfb(rr[0][c]); p4[1]=bfb(rr[1][c]);
    p4[2]=bfb(rr[2][c]); p4[3]=bfb(rr[3][c]);
    *(ushort4v*)(vd + d * 128 + ((vr * 2) ^ SWZ(d))) = p4;
  }
}

template<bool PRE>
__global__ __launch_bounds__(256)
void attn_fwd(const float* __restrict__ Q, const float* __restrict__ K,
              const float* __restrict__ V, const int* __restrict__ M,
              const uint* __restrict__ F, const char* __restrict__ kws,
              const char* __restrict__ vws, float* __restrict__ O)
{
  // double-buffered K/V (T3): 40.9 KB -> 4 wg/CU; loads stay in flight
  __shared__ __align__(16) ushort kb[2][KVBLK * DH];
  __shared__ __align__(16) ushort vb[2][DH * KVBLK];
  __shared__ __align__(16) uint   pbw[NWAVE * 16 * 32];

  const int tid  = threadIdx.x;
  const int lane = tid & 63;
  const int w    = tid >> 6;
  const int qr   = lane & 15;
  const int kg   = lane >> 4;

  // XCD-aware bijective block swizzle (2048 % 8 == 0)
  const int flat = blockIdx.y * gridDim.x + blockIdx.x;
  const int nid  = (flat & 7) * 256 + (flat >> 3);
  const int q0   = (nid & 31) * QBLK;
  const int bh   = nid >> 5;

  const float* Qb = Q + ((size_t)bh * S_LEN) * DH;
  const float* Kb = K + ((size_t)bh * S_LEN) * DH;
  const float* Vb = V + ((size_t)bh * S_LEN) * DH;

  const uint fmask = PRE ? F[q0 / QBLK] : 0u;

  // ---- Q fragments (lane maps of A and B coincide; used as B operand) ----
  bf16x8 qf[2];
  {
    const float* qp = Qb + (size_t)(q0 + w * 16 + qr) * DH + kg * 8;
#pragma unroll
    for (int ks = 0; ks < 2; ++ks) {
      float4 a = *(const float4*)(qp + ks * 32);
      float4 b = *(const float4*)(qp + ks * 32 + 4);
      bf16x8 t2;
      t2[0]=(bf16)(a.x*QSCALE); t2[1]=(bf16)(a.y*QSCALE);
      t2[2]=(bf16)(a.z*QSCALE); t2[3]=(bf16)(a.w*QSCALE);
      t2[4]=(bf16)(b.x*QSCALE); t2[5]=(bf16)(b.y*QSCALE);
      t2[6]=(bf16)(b.z*QSCALE); t2[7]=(bf16)(b.w*QSCALE);
      qf[ks] = t2;
    }
  }

  f32x4 acc[4];
#pragma unroll
  for (int nt = 0; nt < 4; ++nt) { f32x4 z = {0.f,0.f,0.f,0.f}; acc[nt] = z; }
  float mrow = -1e30f;
  float rsum = 0.f;

  // loop-invariant LDS byte offsets (buffer base added as compile-time const)
  int lofs[4][2];
#pragma unroll
  for (int x = 0; x < 4; ++x) {
    const int row = 16 * x + qr;
    const int sw  = SWZ(row);
#pragma unroll
    for (int ks = 0; ks < 2; ++ks)
      lofs[x][ks] = row * 128 + ((kg * 16 + 64 * ks) ^ sw);
  }
  char* pb = (char*)pbw + (w * 16 + qr) * 128;
  const int psw = (qr & 7) << 4;

  // ---- shared per-tile compute (reads buffer base pointers) ----
  auto compute = [&](int t, const char* kbB, const char* vbB) {
    f32x4 sc[4];
    __builtin_amdgcn_s_setprio(1);
#pragma unroll
    for (int ct = 0; ct < 4; ++ct) {
      f32x4 z = {0.f,0.f,0.f,0.f};
      sc[ct] = z;
#pragma unroll
      for (int ks = 0; ks < 2; ++ks) {
        bf16x8 kf = *(const bf16x8*)(kbB + lofs[ct][ks]);
        sc[ct] = __builtin_amdgcn_mfma_f32_16x16x32_bf16(kf, qf[ks], sc[ct], 0,0,0);
      }
    }
    __builtin_amdgcn_s_setprio(0);

    const bool allset = PRE ? (((fmask >> t) & 1u) != 0u) : false;
    if (!allset) {
      const size_t mo = (size_t)(q0 + w * 16 + qr) * S_LEN + t * KVBLK + 4 * kg;
#pragma unroll
      for (int ct = 0; ct < 4; ++ct)
#pragma unroll
        for (int r = 0; r < 4; ++r)
          if (M[mo + 16 * ct + r] == 0) sc[ct][r] = NEG;
    }

    float a0 = fmaxf(fmaxf(sc[0][0], sc[0][1]), sc[0][2]);
    float a1 = fmaxf(fmaxf(sc[0][3], sc[1][0]), sc[1][1]);
    float a2 = fmaxf(fmaxf(sc[1][2], sc[1][3]), sc[2][0]);
    float a3 = fmaxf(fmaxf(sc[2][1], sc[2][2]), sc[2][3]);
    float a4 = fmaxf(fmaxf(sc[3][0], sc[3][1]), sc[3][2]);
    float lm = fmaxf(fmaxf(a0, a1), a2);
    lm = fmaxf(fmaxf(lm, a3), a4);
    lm = fmaxf(lm, sc[3][3]);
    lm = fmaxf(lm, __shfl_xor(lm, 16));
    lm = fmaxf(lm, __shfl_xor(lm, 32));

    if (!__all(lm - mrow <= THR)) {    // defer-max (T13)
      const float mnew = fmaxf(mrow, lm);
      const float corr = __builtin_amdgcn_exp2f(mrow - mnew);
      rsum *= corr;
#pragma unroll
      for (int nt = 0; nt < 4; ++nt) acc[nt] *= corr;
      mrow = mnew;
    }

    float p[4][4];
    float ps = 0.f;
#pragma unroll
    for (int ct = 0; ct < 4; ++ct)
#pragma unroll
      for (int r = 0; r < 4; ++r) {
        p[ct][r] = __builtin_amdgcn_exp2f(sc[ct][r] - mrow);
        ps += p[ct][r];
      }
    rsum += ps;

#pragma unroll
    for (int ct = 0; ct < 4; ++ct) {
      uint2v d2;
      d2[0] = cvtpk(p[ct][0], p[ct][1]);
      d2[1] = cvtpk(p[ct][2], p[ct][3]);
      *(uint2v*)(pb + ((32 * ct + 8 * kg) ^ psw)) = d2;
    }

    __builtin_amdgcn_s_setprio(1);
#pragma unroll
    for (int ks = 0; ks < 2; ++ks) {
      bf16x8 pf = *(const bf16x8*)(pb + ((kg * 16 + 64 * ks) ^ psw));
#pragma unroll
      for (int nt = 0; nt < 4; ++nt) {
        bf16x8 vf = *(const bf16x8*)(vbB + lofs[nt][ks]);
        acc[nt] = __builtin_amdgcn_mfma_f32_16x16x32_bf16(vf, pf, acc[nt], 0,0,0);
      }
    }
    __builtin_amdgcn_s_setprio(0);
  };

  if constexpr (PRE) {
    // ---- T3/T4 pipeline: counted vmcnt, raw barriers, x2-unrolled ----
    auto issue = [&](int b, int t) {
      const char* ksrc = kws + ((size_t)bh * NT + t) * TILE_BYTES;
      const char* vsrc = vws + ((size_t)bh * NT + t) * TILE_BYTES;
#pragma unroll
      for (int c = 0; c < 2; ++c) {
        const int off = (w + c * 4) * 1024 + lane * 16;
        gload16(ksrc + off, (char*)kb[b] + off);
        gload16(vsrc + off, (char*)vb[b] + off);
      }
    };

    issue(0, 0);
    for (int t = 0; t < NT; t += 2) {
      // -------- even tile (buffer 0) --------
      issue(1, t + 1);                       // prefetch stays in flight
      asm volatile("s_waitcnt vmcnt(4)" ::: "memory");  // tile t's 4 loads done
      __builtin_amdgcn_s_barrier();
      asm volatile("" ::: "memory");
      compute(t, (const char*)kb[0], (const char*)vb[0]);
      asm volatile("" ::: "memory");
      __builtin_amdgcn_s_barrier();          // all reads of buf0 done
      asm volatile("" ::: "memory");
      // -------- odd tile (buffer 1) --------
      if (t + 2 < NT) {
        issue(0, t + 2);
        asm volatile("s_waitcnt vmcnt(4)" ::: "memory");
      } else {
        asm volatile("s_waitcnt vmcnt(0)" ::: "memory");  // tail: drain
      }
      __builtin_amdgcn_s_barrier();
      asm volatile("" ::: "memory");
      compute(t + 1, (const char*)kb[1], (const char*)vb[1]);
      asm volatile("" ::: "memory");
      __builtin_amdgcn_s_barrier();
      asm volatile("" ::: "memory");
    }
  } else {
    // ---- fallback: single-buffer direct-from-fp32 staging (R4 path) ----
    const int kr0 = tid >> 3, kc8 = tid & 7;
    const int vr = (tid >> 4) * 4, vc = (tid & 15) * 4;
    for (int t = 0; t < NT; ++t) {
      const int kv0 = t * KVBLK;
#pragma unroll
      for (int h = 0; h < 2; ++h) {
        const int row = kr0 + 32 * h;
        const float* kp = Kb + (size_t)(kv0 + row) * DH + kc8 * 8;
        float4 a = *(const float4*)kp;
        float4 b = *(const float4*)(kp + 4);
        ushort8v pk;
        pk[0]=bfb(a.x); pk[1]=bfb(a.y); pk[2]=bfb(a.z); pk[3]=bfb(a.w);
        pk[4]=bfb(b.x); pk[5]=bfb(b.y); pk[6]=bfb(b.z); pk[7]=bfb(b.w);
        *(ushort8v*)((char*)kb[0] + row * 128 + ((kc8 * 16) ^ SWZ(row))) = pk;
      }
      float rr[4][4];
#pragma unroll
      for (int i = 0; i < 4; ++i)
        *(float4*)rr[i] = *(const float4*)(Vb + (size_t)(kv0 + vr + i) * DH + vc);
#pragma unroll
      for (int c = 0; c < 4; ++c) {
        const int d = vc + c;
        ushort4v p4;
        p4[0]=bfb(rr[0][c]); p4[1]=bfb(rr[1][c]);
        p4[2]=bfb(rr[2][c]); p4[3]=bfb(rr[3][c]);
        *(ushort4v*)((char*)vb[0] + d * 128 + ((vr * 2) ^ SWZ(d))) = p4;
      }
      __syncthreads();
      compute(t, (const char*)kb[0], (const char*)vb[0]);
      __syncthreads();
    }
  }

  // ---- epilogue ----
  rsum += __shfl_xor(rsum, 16);
  rsum += __shfl_xor(rsum, 32);
  const float inv = 1.0f / rsum;
  float* Ob = O + ((size_t)bh * S_LEN + q0 + w * 16 + qr) * DH;
#pragma unroll
  for (int nt = 0; nt < 4; ++nt) {
    float4 o = { acc[nt][0] * inv, acc[nt][1] * inv,
                 acc[nt][2] * inv, acc[nt][3] * inv };
    *(float4*)(Ob + 16 * nt + 4 * kg) = o;
  }
}

extern "C" void kernel_launch(void* const* d_in, const int* in_sizes, int n_in,
                              void* d_out, int out_size, void* d_ws, size_t ws_size,
                              hipStream_t stream)
{
  const float* Q = (const float*)d_in[0];
  const float* K = (const float*)d_in[1];
  const float* V = (const float*)d_in[2];
  const int*   M = (const int*)d_in[3];
  float* O = (float*)d_out;

  const size_t need = 4096 + 2 * KV_BYTES;
  const bool pre = (d_ws != nullptr) && (ws_size >= need);

  dim3 grid(S_LEN / QBLK, 4 * 16);
  if (pre) {
    uint* F   = (uint*)d_ws;
    char* kws = (char*)d_ws + 4096;
    char* vws = kws + KV_BYTES;
    mask_flags<<<32, 256, 0, stream>>>(M, F);
    cvt_kv<<<dim3(NT, 64), 256, 0, stream>>>(K, V, kws, vws);
    attn_fwd<true><<<grid, NWAVE * 64, 0, stream>>>(Q, K, V, M, F, kws, vws, O);
  } else {
    attn_fwd<false><<<grid, NWAVE * 64, 0, stream>>>(Q, K, V, M, nullptr, nullptr, nullptr, O);
  }
}

// Round 6
// 138.787 us; speedup vs baseline: 1.2672x; 1.2672x over previous
//
#include <hip/hip_runtime.h>

typedef __bf16 bf16;
typedef __attribute__((ext_vector_type(8))) __bf16 bf16x8;
typedef __attribute__((ext_vector_type(8))) ushort ushort8v;
typedef __attribute__((ext_vector_type(4))) ushort ushort4v;
typedef __attribute__((ext_vector_type(2))) uint uint2v;
typedef __attribute__((ext_vector_type(4))) float f32x4;

constexpr int S_LEN = 2048;
constexpr int DH    = 64;
constexpr int QBLK  = 128;                       // 4 waves x 32 q-rows
constexpr int KVBLK = 64;
constexpr int NWAVE = 4;
constexpr int NT    = S_LEN / KVBLK;             // 32 kv tiles
constexpr float QSCALE = 0.125f * 1.44269504088896f;  // 1/sqrt(64) * log2(e)
constexpr float NEG    = -1.44269504e9f;         // -1e9 in log2 domain
constexpr float THR    = 8.0f;                   // defer-max threshold (T13)
constexpr size_t TILE_BYTES = (size_t)KVBLK * DH * 2;       // 8 KiB
constexpr size_t KV_BYTES   = (size_t)64 * NT * TILE_BYTES; // 16 MiB per tensor

__device__ __forceinline__ ushort bfb(float f) {
  bf16 b = (bf16)f;
  return __builtin_bit_cast(ushort, b);
}
__device__ __forceinline__ int SWZ(int row) {
  return ((row & 7) ^ ((row >> 3) & 7)) << 4;
}
__device__ __forceinline__ uint cvtpk(float lo, float hi) {
  uint r;
  asm("v_cvt_pk_bf16_f32 %0, %1, %2" : "=v"(r) : "v"(lo), "v"(hi));
  return r;
}
__device__ __forceinline__ void gload16(const char* g, void* l) {
  __builtin_amdgcn_global_load_lds(
      (__attribute__((address_space(1))) void*)(g),
      (__attribute__((address_space(3))) void*)(l), 16, 0, 0);
}

// ---- prepass: per 64-q-row block, 32-bit mask of all-ones 64x64 tiles ----
__global__ __launch_bounds__(256)
void mask_flags(const int* __restrict__ M, uint* __restrict__ F) {
  const int qt = blockIdx.x;
  const int tid = threadIdx.x;
  const int r  = tid >> 2;
  const int c0 = (tid & 3) * 16;
  __shared__ int s[4];
  uint bits = 0;
  for (int kt = 0; kt < NT; ++kt) {
    const int* row = M + (size_t)(qt * 64 + r) * S_LEN + kt * 64 + c0;
    int ok = 1;
#pragma unroll
    for (int i = 0; i < 4; ++i) {
      int4 v = *(const int4*)(row + i * 4);
      ok &= (v.x != 0) & (v.y != 0) & (v.z != 0) & (v.w != 0);
    }
    ok = __all(ok) ? 1 : 0;
    if ((tid & 63) == 0) s[tid >> 6] = ok;
    __syncthreads();
    if (s[0] & s[1] & s[2] & s[3]) bits |= 1u << kt;
    __syncthreads();
  }
  if (tid == 0) F[qt] = bits;
}

// ---- prepass: K -> bf16 swizzled tile blobs; V -> V^T bf16 swizzled blobs ----
__global__ __launch_bounds__(256)
void cvt_kv(const float* __restrict__ K, const float* __restrict__ V,
            char* __restrict__ kws, char* __restrict__ vws) {
  const int t = blockIdx.x, bh = blockIdx.y, tid = threadIdx.x;
  const float* Kb = K + ((size_t)bh * S_LEN + t * KVBLK) * DH;
  const float* Vb = V + ((size_t)bh * S_LEN + t * KVBLK) * DH;
  char* kd = kws + ((size_t)bh * NT + t) * TILE_BYTES;
  char* vd = vws + ((size_t)bh * NT + t) * TILE_BYTES;

  const int kr0 = tid >> 3, kc8 = tid & 7;
#pragma unroll
  for (int h = 0; h < 2; ++h) {
    const int row = kr0 + 32 * h;
    const float* kp = Kb + (size_t)row * DH + kc8 * 8;
    float4 a = *(const float4*)kp;
    float4 b = *(const float4*)(kp + 4);
    ushort8v pk;
    pk[0]=bfb(a.x); pk[1]=bfb(a.y); pk[2]=bfb(a.z); pk[3]=bfb(a.w);
    pk[4]=bfb(b.x); pk[5]=bfb(b.y); pk[6]=bfb(b.z); pk[7]=bfb(b.w);
    *(ushort8v*)(kd + row * 128 + ((kc8 * 16) ^ SWZ(row))) = pk;
  }
  const int vr = (tid >> 4) * 4, vc = (tid & 15) * 4;
  float rr[4][4];
#pragma unroll
  for (int i = 0; i < 4; ++i)
    *(float4*)rr[i] = *(const float4*)(Vb + (size_t)(vr + i) * DH + vc);
#pragma unroll
  for (int c = 0; c < 4; ++c) {
    const int d = vc + c;
    ushort4v p4;
    p4[0]=bfb(rr[0][c]); p4[1]=bfb(rr[1][c]);
    p4[2]=bfb(rr[2][c]); p4[3]=bfb(rr[3][c]);
    *(ushort4v*)(vd + d * 128 + ((vr * 2) ^ SWZ(d))) = p4;
  }
}

template<bool PRE>
__global__ __launch_bounds__(256, 4)
void attn_fwd(const float* __restrict__ Q, const float* __restrict__ K,
              const float* __restrict__ V, const int* __restrict__ M,
              const uint* __restrict__ F, const char* __restrict__ kws,
              const char* __restrict__ vws, float* __restrict__ O)
{
  // single-buffered K/V + per-wave P: 32 KB -> 4 wg/CU resident
  __shared__ __align__(16) ushort kb[KVBLK * DH];        // [kv][d] swizzled
  __shared__ __align__(16) ushort vb[DH * KVBLK];        // [d][kv] swizzled
  __shared__ __align__(16) uint   pbw[NWAVE * 32 * 32];  // 32 q-rows/wave

  const int tid  = threadIdx.x;
  const int lane = tid & 63;
  const int w    = tid >> 6;
  const int qr   = lane & 15;
  const int kg   = lane >> 4;

  // XCD-aware bijective block swizzle (1024 % 8 == 0)
  const int flat = blockIdx.y * gridDim.x + blockIdx.x;
  const int nid  = (flat & 7) * 128 + (flat >> 3);
  const int q0   = (nid & 15) * QBLK;
  const int bh   = nid >> 4;

  const float* Qb = Q + ((size_t)bh * S_LEN) * DH;
  const float* Kb = K + ((size_t)bh * S_LEN) * DH;
  const float* Vb = V + ((size_t)bh * S_LEN) * DH;

  // all-ones flags for both 64-row halves of this 128-row q-block
  const uint fmask = PRE ? (F[(q0 >> 6)] & F[(q0 >> 6) + 1]) : 0u;

  // ---- Q fragments, 2 per wave (rows w*32 + f*16 + qr) ----
  bf16x8 qf[2][2];
#pragma unroll
  for (int f = 0; f < 2; ++f) {
    const float* qp = Qb + (size_t)(q0 + w * 32 + f * 16 + qr) * DH + kg * 8;
#pragma unroll
    for (int ks = 0; ks < 2; ++ks) {
      float4 a = *(const float4*)(qp + ks * 32);
      float4 b = *(const float4*)(qp + ks * 32 + 4);
      bf16x8 t2;
      t2[0]=(bf16)(a.x*QSCALE); t2[1]=(bf16)(a.y*QSCALE);
      t2[2]=(bf16)(a.z*QSCALE); t2[3]=(bf16)(a.w*QSCALE);
      t2[4]=(bf16)(b.x*QSCALE); t2[5]=(bf16)(b.y*QSCALE);
      t2[6]=(bf16)(b.z*QSCALE); t2[7]=(bf16)(b.w*QSCALE);
      qf[f][ks] = t2;
    }
  }

  f32x4 acc[2][4];
#pragma unroll
  for (int f = 0; f < 2; ++f)
#pragma unroll
    for (int nt = 0; nt < 4; ++nt) { f32x4 z = {0.f,0.f,0.f,0.f}; acc[f][nt] = z; }
  float mrow[2] = {-1e30f, -1e30f};
  float rsum[2] = {0.f, 0.f};

  // loop-invariant LDS byte offsets (K-read and V-read formulas coincide)
  int lofs[4][2];
#pragma unroll
  for (int x = 0; x < 4; ++x) {
    const int row = 16 * x + qr;
    const int sw  = SWZ(row);
#pragma unroll
    for (int ks = 0; ks < 2; ++ks)
      lofs[x][ks] = row * 128 + ((kg * 16 + 64 * ks) ^ sw);
  }
  char* pb0 = (char*)pbw + (w * 32 + qr) * 128;        // frag 0 row
  char* pb1 = pb0 + 16 * 128;                          // frag 1 row
  const int psw = (qr & 7) << 4;

  // staging decomposition (fallback path)
  const int kr0 = tid >> 3, kc8 = tid & 7;
  const int vr = (tid >> 4) * 4, vc = (tid & 15) * 4;

  for (int t = 0; t < NT; ++t) {
    // ---- stage tile t ----
    if (PRE) {
      const char* ksrc = kws + ((size_t)bh * NT + t) * TILE_BYTES;
      const char* vsrc = vws + ((size_t)bh * NT + t) * TILE_BYTES;
#pragma unroll
      for (int c = 0; c < 2; ++c) {
        const int off = (w + c * 4) * 1024 + lane * 16;
        gload16(ksrc + off, (char*)kb + off);
        gload16(vsrc + off, (char*)vb + off);
      }
    } else {
      const int kv0 = t * KVBLK;
#pragma unroll
      for (int h = 0; h < 2; ++h) {
        const int row = kr0 + 32 * h;
        const float* kp = Kb + (size_t)(kv0 + row) * DH + kc8 * 8;
        float4 a = *(const float4*)kp;
        float4 b = *(const float4*)(kp + 4);
        ushort8v pk;
        pk[0]=bfb(a.x); pk[1]=bfb(a.y); pk[2]=bfb(a.z); pk[3]=bfb(a.w);
        pk[4]=bfb(b.x); pk[5]=bfb(b.y); pk[6]=bfb(b.z); pk[7]=bfb(b.w);
        *(ushort8v*)((char*)kb + row * 128 + ((kc8 * 16) ^ SWZ(row))) = pk;
      }
      float rr[4][4];
#pragma unroll
      for (int i = 0; i < 4; ++i)
        *(float4*)rr[i] = *(const float4*)(Vb + (size_t)(kv0 + vr + i) * DH + vc);
#pragma unroll
      for (int c = 0; c < 4; ++c) {
        const int d = vc + c;
        ushort4v p4;
        p4[0]=bfb(rr[0][c]); p4[1]=bfb(rr[1][c]);
        p4[2]=bfb(rr[2][c]); p4[3]=bfb(rr[3][c]);
        *(ushort4v*)((char*)vb + d * 128 + ((vr * 2) ^ SWZ(d))) = p4;
      }
    }
    __syncthreads();   // staged tile visible

    // ---- S^T = K Q^T, both q-frags share every K-fragment read ----
    f32x4 sc[2][4];
    __builtin_amdgcn_s_setprio(1);
#pragma unroll
    for (int ct = 0; ct < 4; ++ct) {
      f32x4 z = {0.f,0.f,0.f,0.f};
      sc[0][ct] = z; sc[1][ct] = z;
#pragma unroll
      for (int ks = 0; ks < 2; ++ks) {
        bf16x8 kf = *(const bf16x8*)((const char*)kb + lofs[ct][ks]);
        sc[0][ct] = __builtin_amdgcn_mfma_f32_16x16x32_bf16(kf, qf[0][ks], sc[0][ct], 0,0,0);
        sc[1][ct] = __builtin_amdgcn_mfma_f32_16x16x32_bf16(kf, qf[1][ks], sc[1][ct], 0,0,0);
      }
    }
    __builtin_amdgcn_s_setprio(0);

    const bool allset = PRE ? (((fmask >> t) & 1u) != 0u) : false;

    // ---- per-frag in-register online softmax + P write ----
#pragma unroll
    for (int f = 0; f < 2; ++f) {
      if (!allset) {
        const size_t mo = (size_t)(q0 + w * 32 + f * 16 + qr) * S_LEN
                          + t * KVBLK + 4 * kg;
#pragma unroll
        for (int ct = 0; ct < 4; ++ct)
#pragma unroll
          for (int r = 0; r < 4; ++r)
            if (M[mo + 16 * ct + r] == 0) sc[f][ct][r] = NEG;
      }

      float a0 = fmaxf(fmaxf(sc[f][0][0], sc[f][0][1]), sc[f][0][2]);
      float a1 = fmaxf(fmaxf(sc[f][0][3], sc[f][1][0]), sc[f][1][1]);
      float a2 = fmaxf(fmaxf(sc[f][1][2], sc[f][1][3]), sc[f][2][0]);
      float a3 = fmaxf(fmaxf(sc[f][2][1], sc[f][2][2]), sc[f][2][3]);
      float a4 = fmaxf(fmaxf(sc[f][3][0], sc[f][3][1]), sc[f][3][2]);
      float lm = fmaxf(fmaxf(a0, a1), a2);
      lm = fmaxf(fmaxf(lm, a3), a4);
      lm = fmaxf(lm, sc[f][3][3]);
      lm = fmaxf(lm, __shfl_xor(lm, 16));
      lm = fmaxf(lm, __shfl_xor(lm, 32));

      if (!__all(lm - mrow[f] <= THR)) {   // defer-max (T13)
        const float mnew = fmaxf(mrow[f], lm);
        const float corr = __builtin_amdgcn_exp2f(mrow[f] - mnew);
        rsum[f] *= corr;
#pragma unroll
        for (int nt = 0; nt < 4; ++nt) acc[f][nt] *= corr;
        mrow[f] = mnew;
      }

      float p[4][4];
      float ps = 0.f;
#pragma unroll
      for (int ct = 0; ct < 4; ++ct)
#pragma unroll
        for (int r = 0; r < 4; ++r) {
          p[ct][r] = __builtin_amdgcn_exp2f(sc[f][ct][r] - mrow[f]);
          ps += p[ct][r];
        }
      rsum[f] += ps;

      char* pb = f ? pb1 : pb0;
#pragma unroll
      for (int ct = 0; ct < 4; ++ct) {
        uint2v d2;
        d2[0] = cvtpk(p[ct][0], p[ct][1]);
        d2[1] = cvtpk(p[ct][2], p[ct][3]);
        *(uint2v*)(pb + ((32 * ct + 8 * kg) ^ psw)) = d2;
      }
    }

    // ---- O^T += V^T P^T, both q-frags share every V-fragment read ----
    __builtin_amdgcn_s_setprio(1);
#pragma unroll
    for (int ks = 0; ks < 2; ++ks) {
      bf16x8 pf0 = *(const bf16x8*)(pb0 + ((kg * 16 + 64 * ks) ^ psw));
      bf16x8 pf1 = *(const bf16x8*)(pb1 + ((kg * 16 + 64 * ks) ^ psw));
#pragma unroll
      for (int nt = 0; nt < 4; ++nt) {
        bf16x8 vf = *(const bf16x8*)((const char*)vb + lofs[nt][ks]);
        acc[0][nt] = __builtin_amdgcn_mfma_f32_16x16x32_bf16(vf, pf0, acc[0][nt], 0,0,0);
        acc[1][nt] = __builtin_amdgcn_mfma_f32_16x16x32_bf16(vf, pf1, acc[1][nt], 0,0,0);
      }
    }
    __builtin_amdgcn_s_setprio(0);

    __syncthreads();   // all reads of tile t done before next stage
  }

  // ---- epilogue ----
#pragma unroll
  for (int f = 0; f < 2; ++f) {
    float rs = rsum[f];
    rs += __shfl_xor(rs, 16);
    rs += __shfl_xor(rs, 32);
    const float inv = 1.0f / rs;
    float* Ob = O + ((size_t)bh * S_LEN + q0 + w * 32 + f * 16 + qr) * DH;
#pragma unroll
    for (int nt = 0; nt < 4; ++nt) {
      float4 o = { acc[f][nt][0] * inv, acc[f][nt][1] * inv,
                   acc[f][nt][2] * inv, acc[f][nt][3] * inv };
      *(float4*)(Ob + 16 * nt + 4 * kg) = o;
    }
  }
}

extern "C" void kernel_launch(void* const* d_in, const int* in_sizes, int n_in,
                              void* d_out, int out_size, void* d_ws, size_t ws_size,
                              hipStream_t stream)
{
  const float* Q = (const float*)d_in[0];
  const float* K = (const float*)d_in[1];
  const float* V = (const float*)d_in[2];
  const int*   M = (const int*)d_in[3];
  float* O = (float*)d_out;

  const size_t need = 4096 + 2 * KV_BYTES;
  const bool pre = (d_ws != nullptr) && (ws_size >= need);

  dim3 grid(S_LEN / QBLK, 4 * 16);   // 16 q-blocks x 64 (b,h) = 1024 wgs
  if (pre) {
    uint* F   = (uint*)d_ws;
    char* kws = (char*)d_ws + 4096;
    char* vws = kws + KV_BYTES;
    mask_flags<<<32, 256, 0, stream>>>(M, F);
    cvt_kv<<<dim3(NT, 64), 256, 0, stream>>>(K, V, kws, vws);
    attn_fwd<true><<<grid, NWAVE * 64, 0, stream>>>(Q, K, V, M, F, kws, vws, O);
  } else {
    attn_fwd<false><<<grid, NWAVE * 64, 0, stream>>>(Q, K, V, M, nullptr, nullptr, nullptr, O);
  }
}

// Round 7
// 137.803 us; speedup vs baseline: 1.2763x; 1.0071x over previous
//
#include <hip/hip_runtime.h>

typedef __bf16 bf16;
typedef __attribute__((ext_vector_type(8))) __bf16 bf16x8;
typedef __attribute__((ext_vector_type(8))) ushort ushort8v;
typedef __attribute__((ext_vector_type(4))) ushort ushort4v;
typedef __attribute__((ext_vector_type(2))) uint uint2v;
typedef __attribute__((ext_vector_type(4))) float f32x4;

constexpr int S_LEN = 2048;
constexpr int DH    = 64;
constexpr int QBLK  = 128;                       // 4 waves x 32 q-rows
constexpr int KVBLK = 64;
constexpr int NWAVE = 4;
constexpr int NT    = S_LEN / KVBLK;             // 32 kv tiles
constexpr float QSCALE = 0.125f * 1.44269504088896f;  // 1/sqrt(64) * log2(e)
constexpr float NEG    = -1.44269504e9f;         // -1e9 in log2 domain
constexpr float THR    = 8.0f;                   // defer-max threshold (T13)
constexpr size_t TILE_BYTES = (size_t)KVBLK * DH * 2;       // 8 KiB
constexpr size_t KV_BYTES   = (size_t)64 * NT * TILE_BYTES; // 16 MiB per tensor

__device__ __forceinline__ ushort bfb(float f) {
  bf16 b = (bf16)f;
  return __builtin_bit_cast(ushort, b);
}
__device__ __forceinline__ int SWZ(int row) {
  return ((row & 7) ^ ((row >> 3) & 7)) << 4;
}
__device__ __forceinline__ uint cvtpk(float lo, float hi) {
  uint r;
  asm("v_cvt_pk_bf16_f32 %0, %1, %2" : "=v"(r) : "v"(lo), "v"(hi));
  return r;
}
__device__ __forceinline__ void gload16(const char* g, void* l) {
  __builtin_amdgcn_global_load_lds(
      (__attribute__((address_space(1))) void*)(g),
      (__attribute__((address_space(3))) void*)(l), 16, 0, 0);
}

// ---- prepass: parallel all-ones tile flags, atomicOr into per-qt bitmask ----
__global__ __launch_bounds__(256)
void mask_flags(const int* __restrict__ M, uint* __restrict__ F) {
  const int qt  = blockIdx.x;
  const int kt0 = blockIdx.y * 4;
  const int tid = threadIdx.x;
  const int r  = tid >> 2;
  const int c0 = (tid & 3) * 16;
  __shared__ int s[4];
  uint bits = 0;
  for (int i = 0; i < 4; ++i) {
    const int kt = kt0 + i;
    const int* row = M + (size_t)(qt * 64 + r) * S_LEN + kt * 64 + c0;
    int ok = 1;
#pragma unroll
    for (int j = 0; j < 4; ++j) {
      int4 v = *(const int4*)(row + j * 4);
      ok &= (v.x != 0) & (v.y != 0) & (v.z != 0) & (v.w != 0);
    }
    ok = __all(ok) ? 1 : 0;
    if ((tid & 63) == 0) s[tid >> 6] = ok;
    __syncthreads();
    if (s[0] & s[1] & s[2] & s[3]) bits |= 1u << kt;
    __syncthreads();
  }
  if (tid == 0) atomicOr(&F[qt], bits);
}

// ---- prepass: K -> bf16 swizzled tile blobs; V -> V^T bf16 swizzled blobs ----
__global__ __launch_bounds__(256)
void cvt_kv(const float* __restrict__ K, const float* __restrict__ V,
            char* __restrict__ kws, char* __restrict__ vws) {
  const int t = blockIdx.x, bh = blockIdx.y, tid = threadIdx.x;
  const float* Kb = K + ((size_t)bh * S_LEN + t * KVBLK) * DH;
  const float* Vb = V + ((size_t)bh * S_LEN + t * KVBLK) * DH;
  char* kd = kws + ((size_t)bh * NT + t) * TILE_BYTES;
  char* vd = vws + ((size_t)bh * NT + t) * TILE_BYTES;

  const int kr0 = tid >> 3, kc8 = tid & 7;
#pragma unroll
  for (int h = 0; h < 2; ++h) {
    const int row = kr0 + 32 * h;
    const float* kp = Kb + (size_t)row * DH + kc8 * 8;
    float4 a = *(const float4*)kp;
    float4 b = *(const float4*)(kp + 4);
    ushort8v pk;
    pk[0]=bfb(a.x); pk[1]=bfb(a.y); pk[2]=bfb(a.z); pk[3]=bfb(a.w);
    pk[4]=bfb(b.x); pk[5]=bfb(b.y); pk[6]=bfb(b.z); pk[7]=bfb(b.w);
    *(ushort8v*)(kd + row * 128 + ((kc8 * 16) ^ SWZ(row))) = pk;
  }
  const int vr = (tid >> 4) * 4, vc = (tid & 15) * 4;
  float rr[4][4];
#pragma unroll
  for (int i = 0; i < 4; ++i)
    *(float4*)rr[i] = *(const float4*)(Vb + (size_t)(vr + i) * DH + vc);
#pragma unroll
  for (int c = 0; c < 4; ++c) {
    const int d = vc + c;
    ushort4v p4;
    p4[0]=bfb(rr[0][c]); p4[1]=bfb(rr[1][c]);
    p4[2]=bfb(rr[2][c]); p4[3]=bfb(rr[3][c]);
    *(ushort4v*)(vd + d * 128 + ((vr * 2) ^ SWZ(d))) = p4;
  }
}

template<bool PRE>
__global__ __launch_bounds__(256, 3)
void attn_fwd(const float* __restrict__ Q, const float* __restrict__ K,
              const float* __restrict__ V, const int* __restrict__ M,
              const uint* __restrict__ F, const char* __restrict__ kws,
              const char* __restrict__ vws, float* __restrict__ O)
{
  // K/V double-buffered (prefetch hides L2 latency under compute): 48 KB
  __shared__ __align__(16) ushort kb[2][KVBLK * DH];     // [kv][d] swizzled
  __shared__ __align__(16) ushort vb[2][DH * KVBLK];     // [d][kv] swizzled
  __shared__ __align__(16) uint   pbw[NWAVE * 32 * 32];  // 32 q-rows/wave

  const int tid  = threadIdx.x;
  const int lane = tid & 63;
  const int w    = tid >> 6;
  const int qr   = lane & 15;
  const int kg   = lane >> 4;

  // XCD-aware bijective block swizzle (1024 % 8 == 0)
  const int flat = blockIdx.y * gridDim.x + blockIdx.x;
  const int nid  = (flat & 7) * 128 + (flat >> 3);
  const int q0   = (nid & 15) * QBLK;
  const int bh   = nid >> 4;

  const float* Qb = Q + ((size_t)bh * S_LEN) * DH;
  const float* Kb = K + ((size_t)bh * S_LEN) * DH;
  const float* Vb = V + ((size_t)bh * S_LEN) * DH;

  // all-ones flags for both 64-row halves of this 128-row q-block
  const uint fmask = PRE ? (F[(q0 >> 6)] & F[(q0 >> 6) + 1]) : 0u;

  // ---- Q fragments, 2 per wave (rows w*32 + f*16 + qr) ----
  bf16x8 qf[2][2];
#pragma unroll
  for (int f = 0; f < 2; ++f) {
    const float* qp = Qb + (size_t)(q0 + w * 32 + f * 16 + qr) * DH + kg * 8;
#pragma unroll
    for (int ks = 0; ks < 2; ++ks) {
      float4 a = *(const float4*)(qp + ks * 32);
      float4 b = *(const float4*)(qp + ks * 32 + 4);
      bf16x8 t2;
      t2[0]=(bf16)(a.x*QSCALE); t2[1]=(bf16)(a.y*QSCALE);
      t2[2]=(bf16)(a.z*QSCALE); t2[3]=(bf16)(a.w*QSCALE);
      t2[4]=(bf16)(b.x*QSCALE); t2[5]=(bf16)(b.y*QSCALE);
      t2[6]=(bf16)(b.z*QSCALE); t2[7]=(bf16)(b.w*QSCALE);
      qf[f][ks] = t2;
    }
  }

  f32x4 acc[2][4];
#pragma unroll
  for (int f = 0; f < 2; ++f)
#pragma unroll
    for (int nt = 0; nt < 4; ++nt) { f32x4 z = {0.f,0.f,0.f,0.f}; acc[f][nt] = z; }
  float mrow[2] = {-1e30f, -1e30f};
  float rsum[2] = {0.f, 0.f};

  // loop-invariant LDS byte offsets (K-read and V-read formulas coincide)
  int lofs[4][2];
#pragma unroll
  for (int x = 0; x < 4; ++x) {
    const int row = 16 * x + qr;
    const int sw  = SWZ(row);
#pragma unroll
    for (int ks = 0; ks < 2; ++ks)
      lofs[x][ks] = row * 128 + ((kg * 16 + 64 * ks) ^ sw);
  }
  char* pb0 = (char*)pbw + (w * 32 + qr) * 128;        // frag 0 row
  char* pb1 = pb0 + 16 * 128;                          // frag 1 row
  const int psw = (qr & 7) << 4;

  // staging decomposition (fallback path)
  const int kr0 = tid >> 3, kc8 = tid & 7;
  const int vr = (tid >> 4) * 4, vc = (tid & 15) * 4;

  // ---- per-tile compute (buffer passed as compile-time-selected base) ----
  auto compute = [&](int t, const char* kbB, const char* vbB) {
    f32x4 sc[2][4];
    __builtin_amdgcn_s_setprio(1);
#pragma unroll
    for (int ct = 0; ct < 4; ++ct) {
      f32x4 z = {0.f,0.f,0.f,0.f};
      sc[0][ct] = z; sc[1][ct] = z;
#pragma unroll
      for (int ks = 0; ks < 2; ++ks) {
        bf16x8 kf = *(const bf16x8*)(kbB + lofs[ct][ks]);
        sc[0][ct] = __builtin_amdgcn_mfma_f32_16x16x32_bf16(kf, qf[0][ks], sc[0][ct], 0,0,0);
        sc[1][ct] = __builtin_amdgcn_mfma_f32_16x16x32_bf16(kf, qf[1][ks], sc[1][ct], 0,0,0);
      }
    }
    __builtin_amdgcn_s_setprio(0);

    const bool allset = PRE ? (((fmask >> t) & 1u) != 0u) : false;

#pragma unroll
    for (int f = 0; f < 2; ++f) {
      if (!allset) {
        const size_t mo = (size_t)(q0 + w * 32 + f * 16 + qr) * S_LEN
                          + t * KVBLK + 4 * kg;
#pragma unroll
        for (int ct = 0; ct < 4; ++ct)
#pragma unroll
          for (int r = 0; r < 4; ++r)
            if (M[mo + 16 * ct + r] == 0) sc[f][ct][r] = NEG;
      }

      float a0 = fmaxf(fmaxf(sc[f][0][0], sc[f][0][1]), sc[f][0][2]);
      float a1 = fmaxf(fmaxf(sc[f][0][3], sc[f][1][0]), sc[f][1][1]);
      float a2 = fmaxf(fmaxf(sc[f][1][2], sc[f][1][3]), sc[f][2][0]);
      float a3 = fmaxf(fmaxf(sc[f][2][1], sc[f][2][2]), sc[f][2][3]);
      float a4 = fmaxf(fmaxf(sc[f][3][0], sc[f][3][1]), sc[f][3][2]);
      float lm = fmaxf(fmaxf(a0, a1), a2);
      lm = fmaxf(fmaxf(lm, a3), a4);
      lm = fmaxf(lm, sc[f][3][3]);
      lm = fmaxf(lm, __shfl_xor(lm, 16));
      lm = fmaxf(lm, __shfl_xor(lm, 32));

      if (!__all(lm - mrow[f] <= THR)) {   // defer-max (T13)
        const float mnew = fmaxf(mrow[f], lm);
        const float corr = __builtin_amdgcn_exp2f(mrow[f] - mnew);
        rsum[f] *= corr;
#pragma unroll
        for (int nt = 0; nt < 4; ++nt) acc[f][nt] *= corr;
        mrow[f] = mnew;
      }

      float p[4][4];
      float ps = 0.f;
#pragma unroll
      for (int ct = 0; ct < 4; ++ct)
#pragma unroll
        for (int r = 0; r < 4; ++r) {
          p[ct][r] = __builtin_amdgcn_exp2f(sc[f][ct][r] - mrow[f]);
          ps += p[ct][r];
        }
      rsum[f] += ps;

      char* pb = f ? pb1 : pb0;
#pragma unroll
      for (int ct = 0; ct < 4; ++ct) {
        uint2v d2;
        d2[0] = cvtpk(p[ct][0], p[ct][1]);
        d2[1] = cvtpk(p[ct][2], p[ct][3]);
        *(uint2v*)(pb + ((32 * ct + 8 * kg) ^ psw)) = d2;
      }
    }

    __builtin_amdgcn_s_setprio(1);
#pragma unroll
    for (int ks = 0; ks < 2; ++ks) {
      bf16x8 pf0 = *(const bf16x8*)(pb0 + ((kg * 16 + 64 * ks) ^ psw));
      bf16x8 pf1 = *(const bf16x8*)(pb1 + ((kg * 16 + 64 * ks) ^ psw));
#pragma unroll
      for (int nt = 0; nt < 4; ++nt) {
        bf16x8 vf = *(const bf16x8*)(vbB + lofs[nt][ks]);
        acc[0][nt] = __builtin_amdgcn_mfma_f32_16x16x32_bf16(vf, pf0, acc[0][nt], 0,0,0);
        acc[1][nt] = __builtin_amdgcn_mfma_f32_16x16x32_bf16(vf, pf1, acc[1][nt], 0,0,0);
      }
    }
    __builtin_amdgcn_s_setprio(0);
  };

  if constexpr (PRE) {
    auto issue = [&](int b, int t) {
      const char* ksrc = kws + ((size_t)bh * NT + t) * TILE_BYTES;
      const char* vsrc = vws + ((size_t)bh * NT + t) * TILE_BYTES;
#pragma unroll
      for (int c = 0; c < 2; ++c) {
        const int off = (w + c * 4) * 1024 + lane * 16;
        gload16(ksrc + off, (char*)kb[b] + off);
        gload16(vsrc + off, (char*)vb[b] + off);
      }
    };

    issue(0, 0);
    __syncthreads();                     // only fully-exposed stage wait
    for (int t = 0; t < NT; t += 2) {
      issue(1, t + 1);                   // prefetch flies during compute(t)
      compute(t, (const char*)kb[0], (const char*)vb[0]);
      __syncthreads();                   // drains prefetch (already landed)
      if (t + 2 < NT) issue(0, t + 2);
      compute(t + 1, (const char*)kb[1], (const char*)vb[1]);
      __syncthreads();
    }
  } else {
    // ---- fallback: single-buffer direct-from-fp32 staging ----
    for (int t = 0; t < NT; ++t) {
      const int kv0 = t * KVBLK;
#pragma unroll
      for (int h = 0; h < 2; ++h) {
        const int row = kr0 + 32 * h;
        const float* kp = Kb + (size_t)(kv0 + row) * DH + kc8 * 8;
        float4 a = *(const float4*)kp;
        float4 b = *(const float4*)(kp + 4);
        ushort8v pk;
        pk[0]=bfb(a.x); pk[1]=bfb(a.y); pk[2]=bfb(a.z); pk[3]=bfb(a.w);
        pk[4]=bfb(b.x); pk[5]=bfb(b.y); pk[6]=bfb(b.z); pk[7]=bfb(b.w);
        *(ushort8v*)((char*)kb[0] + row * 128 + ((kc8 * 16) ^ SWZ(row))) = pk;
      }
      float rr[4][4];
#pragma unroll
      for (int i = 0; i < 4; ++i)
        *(float4*)rr[i] = *(const float4*)(Vb + (size_t)(kv0 + vr + i) * DH + vc);
#pragma unroll
      for (int c = 0; c < 4; ++c) {
        const int d = vc + c;
        ushort4v p4;
        p4[0]=bfb(rr[0][c]); p4[1]=bfb(rr[1][c]);
        p4[2]=bfb(rr[2][c]); p4[3]=bfb(rr[3][c]);
        *(ushort4v*)((char*)vb[0] + d * 128 + ((vr * 2) ^ SWZ(d))) = p4;
      }
      __syncthreads();
      compute(t, (const char*)kb[0], (const char*)vb[0]);
      __syncthreads();
    }
  }

  // ---- epilogue ----
#pragma unroll
  for (int f = 0; f < 2; ++f) {
    float rs = rsum[f];
    rs += __shfl_xor(rs, 16);
    rs += __shfl_xor(rs, 32);
    const float inv = 1.0f / rs;
    float* Ob = O + ((size_t)bh * S_LEN + q0 + w * 32 + f * 16 + qr) * DH;
#pragma unroll
    for (int nt = 0; nt < 4; ++nt) {
      float4 o = { acc[f][nt][0] * inv, acc[f][nt][1] * inv,
                   acc[f][nt][2] * inv, acc[f][nt][3] * inv };
      *(float4*)(Ob + 16 * nt + 4 * kg) = o;
    }
  }
}

extern "C" void kernel_launch(void* const* d_in, const int* in_sizes, int n_in,
                              void* d_out, int out_size, void* d_ws, size_t ws_size,
                              hipStream_t stream)
{
  const float* Q = (const float*)d_in[0];
  const float* K = (const float*)d_in[1];
  const float* V = (const float*)d_in[2];
  const int*   M = (const int*)d_in[3];
  float* O = (float*)d_out;

  const size_t need = 4096 + 2 * KV_BYTES;
  const bool pre = (d_ws != nullptr) && (ws_size >= need);

  dim3 grid(S_LEN / QBLK, 4 * 16);   // 16 q-blocks x 64 (b,h) = 1024 wgs
  if (pre) {
    uint* F   = (uint*)d_ws;
    char* kws = (char*)d_ws + 4096;
    char* vws = kws + KV_BYTES;
    hipMemsetAsync(F, 0, 32 * sizeof(uint), stream);
    mask_flags<<<dim3(32, 8), 256, 0, stream>>>(M, F);
    cvt_kv<<<dim3(NT, 64), 256, 0, stream>>>(K, V, kws, vws);
    attn_fwd<true><<<grid, NWAVE * 64, 0, stream>>>(Q, K, V, M, F, kws, vws, O);
  } else {
    attn_fwd<false><<<grid, NWAVE * 64, 0, stream>>>(Q, K, V, M, nullptr, nullptr, nullptr, O);
  }
}

// Round 8
// 126.402 us; speedup vs baseline: 1.3914x; 1.0902x over previous
//
#include <hip/hip_runtime.h>

typedef __bf16 bf16;
typedef __attribute__((ext_vector_type(8))) __bf16 bf16x8;
typedef __attribute__((ext_vector_type(8))) ushort ushort8v;
typedef __attribute__((ext_vector_type(4))) ushort ushort4v;
typedef __attribute__((ext_vector_type(2))) uint uint2v;
typedef __attribute__((ext_vector_type(4))) float f32x4;

constexpr int S_LEN = 2048;
constexpr int DH    = 64;
constexpr int KVBLK = 64;
constexpr int NT    = S_LEN / KVBLK;             // 32 kv tiles
constexpr int QW    = 64;                        // q-rows per wave (4 frags)
constexpr float QSCALE = 0.125f * 1.44269504088896f;  // 1/sqrt(64) * log2(e)
constexpr float NEG    = -1.44269504e9f;         // -1e9 in log2 domain
constexpr float THR    = 8.0f;                   // defer-max threshold (T13)
constexpr size_t TILE_BYTES = (size_t)KVBLK * DH * 2;       // 8 KiB
constexpr size_t KV_BYTES   = (size_t)64 * NT * TILE_BYTES; // 16 MiB per tensor

__device__ __forceinline__ ushort bfb(float f) {
  bf16 b = (bf16)f;
  return __builtin_bit_cast(ushort, b);
}
__device__ __forceinline__ int SWZ(int row) {
  return ((row & 7) ^ ((row >> 3) & 7)) << 4;
}
__device__ __forceinline__ uint cvtpk(float lo, float hi) {
  uint r;
  asm("v_cvt_pk_bf16_f32 %0, %1, %2" : "=v"(r) : "v"(lo), "v"(hi));
  return r;
}

// ---- prepass: parallel all-ones tile flags, atomicOr into per-qt bitmask ----
__global__ __launch_bounds__(256)
void mask_flags(const int* __restrict__ M, uint* __restrict__ F) {
  const int qt  = blockIdx.x;
  const int kt0 = blockIdx.y * 4;
  const int tid = threadIdx.x;
  const int r  = tid >> 2;
  const int c0 = (tid & 3) * 16;
  __shared__ int s[4];
  uint bits = 0;
  for (int i = 0; i < 4; ++i) {
    const int kt = kt0 + i;
    const int* row = M + (size_t)(qt * 64 + r) * S_LEN + kt * 64 + c0;
    int ok = 1;
#pragma unroll
    for (int j = 0; j < 4; ++j) {
      int4 v = *(const int4*)(row + j * 4);
      ok &= (v.x != 0) & (v.y != 0) & (v.z != 0) & (v.w != 0);
    }
    ok = __all(ok) ? 1 : 0;
    if ((tid & 63) == 0) s[tid >> 6] = ok;
    __syncthreads();
    if (s[0] & s[1] & s[2] & s[3]) bits |= 1u << kt;
    __syncthreads();
  }
  if (tid == 0) atomicOr(&F[qt], bits);
}

// ---- prepass: K -> bf16 swizzled tile blobs; V -> V^T bf16 swizzled blobs ----
__global__ __launch_bounds__(256)
void cvt_kv(const float* __restrict__ K, const float* __restrict__ V,
            char* __restrict__ kws, char* __restrict__ vws) {
  const int t = blockIdx.x, bh = blockIdx.y, tid = threadIdx.x;
  const float* Kb = K + ((size_t)bh * S_LEN + t * KVBLK) * DH;
  const float* Vb = V + ((size_t)bh * S_LEN + t * KVBLK) * DH;
  char* kd = kws + ((size_t)bh * NT + t) * TILE_BYTES;
  char* vd = vws + ((size_t)bh * NT + t) * TILE_BYTES;

  const int kr0 = tid >> 3, kc8 = tid & 7;
#pragma unroll
  for (int h = 0; h < 2; ++h) {
    const int row = kr0 + 32 * h;
    const float* kp = Kb + (size_t)row * DH + kc8 * 8;
    float4 a = *(const float4*)kp;
    float4 b = *(const float4*)(kp + 4);
    ushort8v pk;
    pk[0]=bfb(a.x); pk[1]=bfb(a.y); pk[2]=bfb(a.z); pk[3]=bfb(a.w);
    pk[4]=bfb(b.x); pk[5]=bfb(b.y); pk[6]=bfb(b.z); pk[7]=bfb(b.w);
    *(ushort8v*)(kd + row * 128 + ((kc8 * 16) ^ SWZ(row))) = pk;
  }
  const int vr = (tid >> 4) * 4, vc = (tid & 15) * 4;
  float rr[4][4];
#pragma unroll
  for (int i = 0; i < 4; ++i)
    *(float4*)rr[i] = *(const float4*)(Vb + (size_t)(vr + i) * DH + vc);
#pragma unroll
  for (int c = 0; c < 4; ++c) {
    const int d = vc + c;
    ushort4v p4;
    p4[0]=bfb(rr[0][c]); p4[1]=bfb(rr[1][c]);
    p4[2]=bfb(rr[2][c]); p4[3]=bfb(rr[3][c]);
    *(ushort4v*)(vd + d * 128 + ((vr * 2) ^ SWZ(d))) = p4;
  }
}

// ---- main: barrier-free, 1 wave/wg, 64 q-rows/wave, K/V direct from L2 ----
__global__ __launch_bounds__(64, 2)
void attn_fwd_direct(const float* __restrict__ Q, const int* __restrict__ M,
                     const uint* __restrict__ F, const char* __restrict__ kws,
                     const char* __restrict__ vws, float* __restrict__ O)
{
  __shared__ __align__(16) uint pbw[QW * 32];   // 8 KB, this wave's P^T

  const int lane = threadIdx.x & 63;
  const int qr   = lane & 15;
  const int kg   = lane >> 4;

  // XCD-aware bijective swizzle (2048 % 8 == 0)
  const int bid = blockIdx.x;
  const int nid = (bid & 7) * 256 + (bid >> 3);
  const int q0  = (nid & 31) * QW;
  const int bh  = nid >> 5;

  const float* Qb = Q + (size_t)bh * S_LEN * DH;
  const uint fmask = F[q0 >> 6];

  const char* kbase = kws + (size_t)bh * NT * TILE_BYTES;
  const char* vbase = vws + (size_t)bh * NT * TILE_BYTES;

  // ---- Q fragments: rows q0 + f*16 + qr ----
  bf16x8 qf[4][2];
#pragma unroll
  for (int f = 0; f < 4; ++f) {
    const float* qp = Qb + (size_t)(q0 + f * 16 + qr) * DH + kg * 8;
#pragma unroll
    for (int ks = 0; ks < 2; ++ks) {
      float4 a = *(const float4*)(qp + ks * 32);
      float4 b = *(const float4*)(qp + ks * 32 + 4);
      bf16x8 t2;
      t2[0]=(bf16)(a.x*QSCALE); t2[1]=(bf16)(a.y*QSCALE);
      t2[2]=(bf16)(a.z*QSCALE); t2[3]=(bf16)(a.w*QSCALE);
      t2[4]=(bf16)(b.x*QSCALE); t2[5]=(bf16)(b.y*QSCALE);
      t2[6]=(bf16)(b.z*QSCALE); t2[7]=(bf16)(b.w*QSCALE);
      qf[f][ks] = t2;
    }
  }

  f32x4 acc[4][4];
#pragma unroll
  for (int f = 0; f < 4; ++f)
#pragma unroll
    for (int nt = 0; nt < 4; ++nt) { f32x4 z = {0.f,0.f,0.f,0.f}; acc[f][nt] = z; }
  float mrow[4] = {-1e30f,-1e30f,-1e30f,-1e30f};
  float rsum[4] = {0.f,0.f,0.f,0.f};

  // fragment byte offsets within a tile blob (loop-invariant)
  int lofs[4][2];
#pragma unroll
  for (int x = 0; x < 4; ++x) {
    const int row = 16 * x + qr;
    const int sw  = SWZ(row);
#pragma unroll
    for (int ks = 0; ks < 2; ++ks)
      lofs[x][ks] = row * 128 + ((kg * 16 + 64 * ks) ^ sw);
  }
  const int psw = (qr & 7) << 4;

  for (int t = 0; t < NT; ++t) {
    const char* kt = kbase + (size_t)t * TILE_BYTES;
    const char* vt = vbase + (size_t)t * TILE_BYTES;

    // ---- S^T = K Q^T : each kf fragment feeds 4 MFMAs ----
    f32x4 sc[4][4];
#pragma unroll
    for (int f = 0; f < 4; ++f)
#pragma unroll
      for (int ct = 0; ct < 4; ++ct) { f32x4 z = {0.f,0.f,0.f,0.f}; sc[f][ct] = z; }

    __builtin_amdgcn_s_setprio(1);
#pragma unroll
    for (int ct = 0; ct < 4; ++ct)
#pragma unroll
      for (int ks = 0; ks < 2; ++ks) {
        bf16x8 kf = *(const bf16x8*)(kt + lofs[ct][ks]);
        sc[0][ct] = __builtin_amdgcn_mfma_f32_16x16x32_bf16(kf, qf[0][ks], sc[0][ct], 0,0,0);
        sc[1][ct] = __builtin_amdgcn_mfma_f32_16x16x32_bf16(kf, qf[1][ks], sc[1][ct], 0,0,0);
        sc[2][ct] = __builtin_amdgcn_mfma_f32_16x16x32_bf16(kf, qf[2][ks], sc[2][ct], 0,0,0);
        sc[3][ct] = __builtin_amdgcn_mfma_f32_16x16x32_bf16(kf, qf[3][ks], sc[3][ct], 0,0,0);
      }
    __builtin_amdgcn_s_setprio(0);

    // ---- issue V fragment loads now; latency hides under softmax ----
    bf16x8 vfr[4][2];
#pragma unroll
    for (int nt = 0; nt < 4; ++nt)
#pragma unroll
      for (int ks = 0; ks < 2; ++ks)
        vfr[nt][ks] = *(const bf16x8*)(vt + lofs[nt][ks]);

    const bool allset = ((fmask >> t) & 1u) != 0u;

    // ---- per-frag in-register online softmax + P pack to LDS ----
#pragma unroll
    for (int f = 0; f < 4; ++f) {
      if (!allset) {
        const size_t mo = (size_t)(q0 + f * 16 + qr) * S_LEN + t * KVBLK + 4 * kg;
#pragma unroll
        for (int ct = 0; ct < 4; ++ct)
#pragma unroll
          for (int r = 0; r < 4; ++r)
            if (M[mo + 16 * ct + r] == 0) sc[f][ct][r] = NEG;
      }

      float a0 = fmaxf(fmaxf(sc[f][0][0], sc[f][0][1]), sc[f][0][2]);
      float a1 = fmaxf(fmaxf(sc[f][0][3], sc[f][1][0]), sc[f][1][1]);
      float a2 = fmaxf(fmaxf(sc[f][1][2], sc[f][1][3]), sc[f][2][0]);
      float a3 = fmaxf(fmaxf(sc[f][2][1], sc[f][2][2]), sc[f][2][3]);
      float a4 = fmaxf(fmaxf(sc[f][3][0], sc[f][3][1]), sc[f][3][2]);
      float lm = fmaxf(fmaxf(a0, a1), a2);
      lm = fmaxf(fmaxf(lm, a3), a4);
      lm = fmaxf(lm, sc[f][3][3]);
      lm = fmaxf(lm, __shfl_xor(lm, 16));
      lm = fmaxf(lm, __shfl_xor(lm, 32));

      if (!__all(lm - mrow[f] <= THR)) {   // defer-max (T13)
        const float mnew = fmaxf(mrow[f], lm);
        const float corr = __builtin_amdgcn_exp2f(mrow[f] - mnew);
        rsum[f] *= corr;
#pragma unroll
        for (int nt = 0; nt < 4; ++nt) acc[f][nt] *= corr;
        mrow[f] = mnew;
      }

      float p[4][4];
      float ps = 0.f;
#pragma unroll
      for (int ct = 0; ct < 4; ++ct)
#pragma unroll
        for (int r = 0; r < 4; ++r) {
          p[ct][r] = __builtin_amdgcn_exp2f(sc[f][ct][r] - mrow[f]);
          ps += p[ct][r];
        }
      rsum[f] += ps;

      char* pb = (char*)pbw + (f * 16 + qr) * 128;
#pragma unroll
      for (int ct = 0; ct < 4; ++ct) {
        uint2v d2;
        d2[0] = cvtpk(p[ct][0], p[ct][1]);
        d2[1] = cvtpk(p[ct][2], p[ct][3]);
        *(uint2v*)(pb + ((32 * ct + 8 * kg) ^ psw)) = d2;
      }
    }

    // ---- O^T += V^T P^T : each vf fragment feeds 4 MFMAs ----
    __builtin_amdgcn_s_setprio(1);
#pragma unroll
    for (int ks = 0; ks < 2; ++ks) {
      bf16x8 pf0 = *(const bf16x8*)((char*)pbw + (0 * 16 + qr) * 128 + ((kg * 16 + 64 * ks) ^ psw));
      bf16x8 pf1 = *(const bf16x8*)((char*)pbw + (1 * 16 + qr) * 128 + ((kg * 16 + 64 * ks) ^ psw));
      bf16x8 pf2 = *(const bf16x8*)((char*)pbw + (2 * 16 + qr) * 128 + ((kg * 16 + 64 * ks) ^ psw));
      bf16x8 pf3 = *(const bf16x8*)((char*)pbw + (3 * 16 + qr) * 128 + ((kg * 16 + 64 * ks) ^ psw));
#pragma unroll
      for (int nt = 0; nt < 4; ++nt) {
        bf16x8 vf = vfr[nt][ks];
        acc[0][nt] = __builtin_amdgcn_mfma_f32_16x16x32_bf16(vf, pf0, acc[0][nt], 0,0,0);
        acc[1][nt] = __builtin_amdgcn_mfma_f32_16x16x32_bf16(vf, pf1, acc[1][nt], 0,0,0);
        acc[2][nt] = __builtin_amdgcn_mfma_f32_16x16x32_bf16(vf, pf2, acc[2][nt], 0,0,0);
        acc[3][nt] = __builtin_amdgcn_mfma_f32_16x16x32_bf16(vf, pf3, acc[3][nt], 0,0,0);
      }
    }
    __builtin_amdgcn_s_setprio(0);
  }

  // ---- epilogue ----
#pragma unroll
  for (int f = 0; f < 4; ++f) {
    float rs = rsum[f];
    rs += __shfl_xor(rs, 16);
    rs += __shfl_xor(rs, 32);
    const float inv = 1.0f / rs;
    float* Ob = O + ((size_t)bh * S_LEN + q0 + f * 16 + qr) * DH;
#pragma unroll
    for (int nt = 0; nt < 4; ++nt) {
      float4 o = { acc[f][nt][0] * inv, acc[f][nt][1] * inv,
                   acc[f][nt][2] * inv, acc[f][nt][3] * inv };
      *(float4*)(Ob + 16 * nt + 4 * kg) = o;
    }
  }
}

// ---- fallback (no workspace): R6 single-buffer kernel, fp32-direct staging --
__global__ __launch_bounds__(256, 4)
void attn_fwd_fb(const float* __restrict__ Q, const float* __restrict__ K,
                 const float* __restrict__ V, const int* __restrict__ M,
                 float* __restrict__ O)
{
  __shared__ __align__(16) ushort kb[KVBLK * DH];
  __shared__ __align__(16) ushort vb[DH * KVBLK];
  __shared__ __align__(16) uint   pbw[4 * 32 * 32];

  const int tid  = threadIdx.x;
  const int lane = tid & 63;
  const int w    = tid >> 6;
  const int qr   = lane & 15;
  const int kg   = lane >> 4;

  const int flat = blockIdx.y * gridDim.x + blockIdx.x;
  const int nid  = (flat & 7) * 128 + (flat >> 3);
  const int q0   = (nid & 15) * 128;
  const int bh   = nid >> 4;

  const float* Qb = Q + ((size_t)bh * S_LEN) * DH;
  const float* Kb = K + ((size_t)bh * S_LEN) * DH;
  const float* Vb = V + ((size_t)bh * S_LEN) * DH;

  bf16x8 qf[2][2];
#pragma unroll
  for (int f = 0; f < 2; ++f) {
    const float* qp = Qb + (size_t)(q0 + w * 32 + f * 16 + qr) * DH + kg * 8;
#pragma unroll
    for (int ks = 0; ks < 2; ++ks) {
      float4 a = *(const float4*)(qp + ks * 32);
      float4 b = *(const float4*)(qp + ks * 32 + 4);
      bf16x8 t2;
      t2[0]=(bf16)(a.x*QSCALE); t2[1]=(bf16)(a.y*QSCALE);
      t2[2]=(bf16)(a.z*QSCALE); t2[3]=(bf16)(a.w*QSCALE);
      t2[4]=(bf16)(b.x*QSCALE); t2[5]=(bf16)(b.y*QSCALE);
      t2[6]=(bf16)(b.z*QSCALE); t2[7]=(bf16)(b.w*QSCALE);
      qf[f][ks] = t2;
    }
  }

  f32x4 acc[2][4];
#pragma unroll
  for (int f = 0; f < 2; ++f)
#pragma unroll
    for (int nt = 0; nt < 4; ++nt) { f32x4 z = {0.f,0.f,0.f,0.f}; acc[f][nt] = z; }
  float mrow[2] = {-1e30f, -1e30f};
  float rsum[2] = {0.f, 0.f};

  int lofs[4][2];
#pragma unroll
  for (int x = 0; x < 4; ++x) {
    const int row = 16 * x + qr;
    const int sw  = SWZ(row);
#pragma unroll
    for (int ks = 0; ks < 2; ++ks)
      lofs[x][ks] = row * 128 + ((kg * 16 + 64 * ks) ^ sw);
  }
  char* pb0 = (char*)pbw + (w * 32 + qr) * 128;
  char* pb1 = pb0 + 16 * 128;
  const int psw = (qr & 7) << 4;

  const int kr0 = tid >> 3, kc8 = tid & 7;
  const int vr = (tid >> 4) * 4, vc = (tid & 15) * 4;

  for (int t = 0; t < NT; ++t) {
    const int kv0 = t * KVBLK;
#pragma unroll
    for (int h = 0; h < 2; ++h) {
      const int row = kr0 + 32 * h;
      const float* kp = Kb + (size_t)(kv0 + row) * DH + kc8 * 8;
      float4 a = *(const float4*)kp;
      float4 b = *(const float4*)(kp + 4);
      ushort8v pk;
      pk[0]=bfb(a.x); pk[1]=bfb(a.y); pk[2]=bfb(a.z); pk[3]=bfb(a.w);
      pk[4]=bfb(b.x); pk[5]=bfb(b.y); pk[6]=bfb(b.z); pk[7]=bfb(b.w);
      *(ushort8v*)((char*)kb + row * 128 + ((kc8 * 16) ^ SWZ(row))) = pk;
    }
    float rr[4][4];
#pragma unroll
    for (int i = 0; i < 4; ++i)
      *(float4*)rr[i] = *(const float4*)(Vb + (size_t)(kv0 + vr + i) * DH + vc);
#pragma unroll
    for (int c = 0; c < 4; ++c) {
      const int d = vc + c;
      ushort4v p4;
      p4[0]=bfb(rr[0][c]); p4[1]=bfb(rr[1][c]);
      p4[2]=bfb(rr[2][c]); p4[3]=bfb(rr[3][c]);
      *(ushort4v*)((char*)vb + d * 128 + ((vr * 2) ^ SWZ(d))) = p4;
    }
    __syncthreads();

    f32x4 sc[2][4];
#pragma unroll
    for (int ct = 0; ct < 4; ++ct) {
      f32x4 z = {0.f,0.f,0.f,0.f};
      sc[0][ct] = z; sc[1][ct] = z;
#pragma unroll
      for (int ks = 0; ks < 2; ++ks) {
        bf16x8 kf = *(const bf16x8*)((const char*)kb + lofs[ct][ks]);
        sc[0][ct] = __builtin_amdgcn_mfma_f32_16x16x32_bf16(kf, qf[0][ks], sc[0][ct], 0,0,0);
        sc[1][ct] = __builtin_amdgcn_mfma_f32_16x16x32_bf16(kf, qf[1][ks], sc[1][ct], 0,0,0);
      }
    }

#pragma unroll
    for (int f = 0; f < 2; ++f) {
      const size_t mo = (size_t)(q0 + w * 32 + f * 16 + qr) * S_LEN + t * KVBLK + 4 * kg;
#pragma unroll
      for (int ct = 0; ct < 4; ++ct)
#pragma unroll
        for (int r = 0; r < 4; ++r)
          if (M[mo + 16 * ct + r] == 0) sc[f][ct][r] = NEG;

      float a0 = fmaxf(fmaxf(sc[f][0][0], sc[f][0][1]), sc[f][0][2]);
      float a1 = fmaxf(fmaxf(sc[f][0][3], sc[f][1][0]), sc[f][1][1]);
      float a2 = fmaxf(fmaxf(sc[f][1][2], sc[f][1][3]), sc[f][2][0]);
      float a3 = fmaxf(fmaxf(sc[f][2][1], sc[f][2][2]), sc[f][2][3]);
      float a4 = fmaxf(fmaxf(sc[f][3][0], sc[f][3][1]), sc[f][3][2]);
      float lm = fmaxf(fmaxf(a0, a1), a2);
      lm = fmaxf(fmaxf(lm, a3), a4);
      lm = fmaxf(lm, sc[f][3][3]);
      lm = fmaxf(lm, __shfl_xor(lm, 16));
      lm = fmaxf(lm, __shfl_xor(lm, 32));

      if (!__all(lm - mrow[f] <= THR)) {
        const float mnew = fmaxf(mrow[f], lm);
        const float corr = __builtin_amdgcn_exp2f(mrow[f] - mnew);
        rsum[f] *= corr;
#pragma unroll
        for (int nt = 0; nt < 4; ++nt) acc[f][nt] *= corr;
        mrow[f] = mnew;
      }

      float p[4][4];
      float ps = 0.f;
#pragma unroll
      for (int ct = 0; ct < 4; ++ct)
#pragma unroll
        for (int r = 0; r < 4; ++r) {
          p[ct][r] = __builtin_amdgcn_exp2f(sc[f][ct][r] - mrow[f]);
          ps += p[ct][r];
        }
      rsum[f] += ps;

      char* pb = f ? pb1 : pb0;
#pragma unroll
      for (int ct = 0; ct < 4; ++ct) {
        uint2v d2;
        d2[0] = cvtpk(p[ct][0], p[ct][1]);
        d2[1] = cvtpk(p[ct][2], p[ct][3]);
        *(uint2v*)(pb + ((32 * ct + 8 * kg) ^ psw)) = d2;
      }
    }

#pragma unroll
    for (int ks = 0; ks < 2; ++ks) {
      bf16x8 pf0 = *(const bf16x8*)(pb0 + ((kg * 16 + 64 * ks) ^ psw));
      bf16x8 pf1 = *(const bf16x8*)(pb1 + ((kg * 16 + 64 * ks) ^ psw));
#pragma unroll
      for (int nt = 0; nt < 4; ++nt) {
        bf16x8 vf = *(const bf16x8*)((const char*)vb + lofs[nt][ks]);
        acc[0][nt] = __builtin_amdgcn_mfma_f32_16x16x32_bf16(vf, pf0, acc[0][nt], 0,0,0);
        acc[1][nt] = __builtin_amdgcn_mfma_f32_16x16x32_bf16(vf, pf1, acc[1][nt], 0,0,0);
      }
    }
    __syncthreads();
  }

#pragma unroll
  for (int f = 0; f < 2; ++f) {
    float rs = rsum[f];
    rs += __shfl_xor(rs, 16);
    rs += __shfl_xor(rs, 32);
    const float inv = 1.0f / rs;
    float* Ob = O + ((size_t)bh * S_LEN + q0 + w * 32 + f * 16 + qr) * DH;
#pragma unroll
    for (int nt = 0; nt < 4; ++nt) {
      float4 o = { acc[f][nt][0] * inv, acc[f][nt][1] * inv,
                   acc[f][nt][2] * inv, acc[f][nt][3] * inv };
      *(float4*)(Ob + 16 * nt + 4 * kg) = o;
    }
  }
}

extern "C" void kernel_launch(void* const* d_in, const int* in_sizes, int n_in,
                              void* d_out, int out_size, void* d_ws, size_t ws_size,
                              hipStream_t stream)
{
  const float* Q = (const float*)d_in[0];
  const float* K = (const float*)d_in[1];
  const float* V = (const float*)d_in[2];
  const int*   M = (const int*)d_in[3];
  float* O = (float*)d_out;

  const size_t need = 4096 + 2 * KV_BYTES;
  const bool pre = (d_ws != nullptr) && (ws_size >= need);

  if (pre) {
    uint* F   = (uint*)d_ws;
    char* kws = (char*)d_ws + 4096;
    char* vws = kws + KV_BYTES;
    hipMemsetAsync(F, 0, 32 * sizeof(uint), stream);
    mask_flags<<<dim3(32, 8), 256, 0, stream>>>(M, F);
    cvt_kv<<<dim3(NT, 64), 256, 0, stream>>>(K, V, kws, vws);
    attn_fwd_direct<<<2048, 64, 0, stream>>>(Q, M, F, kws, vws, O);
  } else {
    attn_fwd_fb<<<dim3(16, 64), 256, 0, stream>>>(Q, K, V, M, O);
  }
}